// Round 6
// baseline (350.824 us; speedup 1.0000x reference)
//
#include <hip/hip_runtime.h>

// GaborBasis: out[b,t,r] = window_norm * cos(z·K[r] + phi[r]),
//   window = exp(-max(|z|^2+|mu_r|^2-2 z·mu_r,0)/(2 sigma_r^2)), normalized over r.
// fp16 hi/lo 3-term split MFMA (16x16x32); fast-math epilogue.
// Round 6: (1) rolling B-fragment register prefetch (round 5 was latency-bound:
// MfmaUtil 29%, B loads issued right before use); (2) normalization fused into
// main via per-panel atomic row-sums + "last block normalizes" (kills the
// ~21us norm pass). No spin-waits -> dispatch-order independent.

typedef _Float16 f16x8 __attribute__((ext_vector_type(8)));
typedef float f32x4 __attribute__((ext_vector_type(4)));

#define M_DIM 16384
#define R_DIM 1024
#define INV2PI 0.15915494309189535f

// ---------------- prep: z_sq[16384], mu_sq[1024], inv2s2[1024], phirev[1024] ----------------
__global__ void gabor_prep(const float* __restrict__ z, const float* __restrict__ mu,
                           const float* __restrict__ ls, const float* __restrict__ phi,
                           float* __restrict__ zsq, float* __restrict__ musq,
                           float* __restrict__ inv2s2, float* __restrict__ phirev) {
    const int lane = threadIdx.x & 63;
    const int wv = threadIdx.x >> 6;
    const int bid = blockIdx.x;
    if (bid < 4096) {
        const int row = bid * 4 + wv;
        float4 v = *(const float4*)(z + (size_t)row * 256 + lane * 4);
        float s = v.x * v.x + v.y * v.y + v.z * v.z + v.w * v.w;
#pragma unroll
        for (int sh = 1; sh < 64; sh <<= 1) s += __shfl_xor(s, sh, 64);
        if (lane == 0) zsq[row] = s;
    } else {
        const int row = (bid - 4096) * 4 + wv;
        float4 v = *(const float4*)(mu + (size_t)row * 256 + lane * 4);
        float s = v.x * v.x + v.y * v.y + v.z * v.z + v.w * v.w;
#pragma unroll
        for (int sh = 1; sh < 64; sh <<= 1) s += __shfl_xor(s, sh, 64);
        if (lane == 0) {
            musq[row] = s;
            float e = expf(ls[row]);
            inv2s2[row] = 1.0f / (2.0f * (e * e + 1e-8f));
            phirev[row] = phi[row] * INV2PI;
        }
    }
}

// ---------------- split: fp32 -> fp16 hi/lo in MFMA-fragment order ----------------
// Layout per matrix: [sub = row/16][ks = k/32][1024 halves]: hi at lane*8, lo at 512+lane*8,
// lane = (row&15) | ((k>>3 & 3)<<4). One thread = one (sub,ks,lane) = 8 fp32.
__global__ void gabor_split(const float* __restrict__ z, const float* __restrict__ mu,
                            const float* __restrict__ Kmat,
                            _Float16* __restrict__ zf, _Float16* __restrict__ muf,
                            _Float16* __restrict__ kf) {
    const int t = blockIdx.x * 256 + threadIdx.x;   // 0..589823
    const float* src; _Float16* dst; int item;
    if (t < 524288)      { item = t;          src = z;    dst = zf; }
    else if (t < 557056) { item = t - 524288; src = mu;   dst = muf; }
    else                 { item = t - 557056; src = Kmat; dst = kf; }
    const int sub = item >> 9, rem = item & 511;
    const int ks = rem >> 6, l = rem & 63;
    const int row = sub * 16 + (l & 15);
    const int k0 = ks * 32 + (l >> 4) * 8;
    const float* sp = src + (size_t)row * 256 + k0;
    float v[8];
    *(float4*)&v[0] = *(const float4*)(sp);
    *(float4*)&v[4] = *(const float4*)(sp + 4);
    f16x8 hi, lo;
#pragma unroll
    for (int j = 0; j < 8; ++j) {
        _Float16 h = (_Float16)v[j];
        hi[j] = h;
        lo[j] = (_Float16)(v[j] - (float)h);
    }
    _Float16* d = dst + (size_t)(sub * 8 + ks) * 1024;
    *(f16x8*)(d + l * 8) = hi;
    *(f16x8*)(d + 512 + l * 8) = lo;
}

// ---------------- main: 128x128 tile, 8 waves (64x32 each), K-step 32 ----------------
// A (z) staged in LDS double-buffered; B (mu,K) fragments direct from global with
// rolling 1-cluster-ahead register prefetch. Last-arriving block normalizes panel.
template <bool PRE>
__global__ __launch_bounds__(512, 2) void gabor_main(
    const float* __restrict__ z, const float* __restrict__ mu, const float* __restrict__ Kmat,
    const _Float16* __restrict__ zf, const _Float16* __restrict__ muf, const _Float16* __restrict__ kf,
    const float* __restrict__ zsq, const float* __restrict__ musq,
    const float* __restrict__ inv2s2, const float* __restrict__ phirev,
    float* __restrict__ out, float* __restrict__ panelSum, int* __restrict__ panelCnt) {
    __shared__ _Float16 sA[2][8192];   // [buf][sub*512 + lane*8] hi; lo at +4096
    __shared__ float sZsq[128], sMusq[128], sInv[128], sPrv[128];
    __shared__ float sRow[4][128];
    __shared__ float sInvN[128];
    __shared__ int sLast;

    const int tid = threadIdx.x;
    const int bid = blockIdx.x;
    const int xcd = bid & 7, kk = bid >> 3;   // kk 0..127
    const int mb = xcd * 16 + (kk >> 3);      // 0..127 (16 row-panels per XCD)
    const int nb = kk & 7;                    // 0..7
    const int rbase = mb * 128, cbase = nb * 128;

    if (tid < 128) {
        sZsq[tid] = zsq[rbase + tid];
        sMusq[tid] = musq[cbase + tid];
        sInv[tid] = inv2s2[cbase + tid];
        sPrv[tid] = phirev[cbase + tid];
    }

    f32x4 accC[4][2], accP[4][2];
#pragma unroll
    for (int i = 0; i < 4; ++i)
#pragma unroll
        for (int j = 0; j < 2; ++j) {
            accC[i][j] = (f32x4){0.f, 0.f, 0.f, 0.f};
            accP[i][j] = (f32x4){0.f, 0.f, 0.f, 0.f};
        }

    const int sub8 = tid >> 6, sl = tid & 63;
    const int lane = tid & 63;
    const int wv = tid >> 6;
    const int wr = wv >> 2;            // 0..1
    const int wc = wv & 3;             // 0..3
    const int lr = lane & 15, lg = lane >> 4;

    const _Float16* zsrc = zf + (size_t)((mb * 8 + sub8) * 8) * 1024 + sl * 8;
    const _Float16* mfp = muf + (size_t)((nb * 8 + wc * 2) * 8) * 1024 + lane * 8;
    const _Float16* kfp = kf  + (size_t)((nb * 8 + wc * 2) * 8) * 1024 + lane * 8;

    f16x8 raH, raL;
    auto loadA = [&](int ks) {
        if constexpr (PRE) {
            const _Float16* p = zsrc + ks * 1024;
            raH = *(const f16x8*)(p);
            raL = *(const f16x8*)(p + 512);
        } else {
            const int row = rbase + sub8 * 16 + (sl & 15);
            const float* sp = z + (size_t)row * 256 + ks * 32 + (sl >> 4) * 8;
            float v[8];
            *(float4*)&v[0] = *(const float4*)(sp);
            *(float4*)&v[4] = *(const float4*)(sp + 4);
#pragma unroll
            for (int j = 0; j < 8; ++j) {
                _Float16 h = (_Float16)v[j];
                raH[j] = h; raL[j] = (_Float16)(v[j] - (float)h);
            }
        }
    };

    auto loadB = [&](int ks, int nf, f16x8& bmH, f16x8& bmL, f16x8& bkH, f16x8& bkL) {
        if constexpr (PRE) {
            const _Float16* mp = mfp + nf * 8192 + ks * 1024;
            bmH = *(const f16x8*)(mp);
            bmL = *(const f16x8*)(mp + 512);
            const _Float16* kp = kfp + nf * 8192 + ks * 1024;
            bkH = *(const f16x8*)(kp);
            bkL = *(const f16x8*)(kp + 512);
        } else {
            const int col = cbase + (wc * 2 + nf) * 16 + lr;
            const int k0 = ks * 32 + lg * 8;
            float v[8];
            const float* sp = mu + (size_t)col * 256 + k0;
            *(float4*)&v[0] = *(const float4*)(sp);
            *(float4*)&v[4] = *(const float4*)(sp + 4);
#pragma unroll
            for (int q = 0; q < 8; ++q) {
                _Float16 h = (_Float16)v[q];
                bmH[q] = h; bmL[q] = (_Float16)(v[q] - (float)h);
            }
            const float* sp2 = Kmat + (size_t)col * 256 + k0;
            *(float4*)&v[0] = *(const float4*)(sp2);
            *(float4*)&v[4] = *(const float4*)(sp2 + 4);
#pragma unroll
            for (int q = 0; q < 8; ++q) {
                _Float16 h = (_Float16)v[q];
                bkH[q] = h; bkL[q] = (_Float16)(v[q] - (float)h);
            }
        }
    };

    f16x8 cbmH, cbmL, cbkH, cbkL;      // current cluster's B
    f16x8 nbmH, nbmL, nbkH, nbkL;      // next cluster's B (in flight)

    loadA(0);
    *(f16x8*)&sA[0][sub8 * 512 + sl * 8] = raH;
    *(f16x8*)&sA[0][4096 + sub8 * 512 + sl * 8] = raL;
    loadB(0, 0, cbmH, cbmL, cbkH, cbkL);
    __syncthreads();

#pragma unroll
    for (int ks = 0; ks < 8; ++ks) {
        const int b = ks & 1;
        f16x8 aH[4], aL[4];
#pragma unroll
        for (int mf = 0; mf < 4; ++mf) {
            const int o = (wr * 4 + mf) * 512 + lane * 8;
            aH[mf] = *(const f16x8*)&sA[b][o];
            aL[mf] = *(const f16x8*)&sA[b][4096 + o];
        }
        if (ks < 7) loadA(ks + 1);                         // A global -> regs
        loadB(ks, 1, nbmH, nbmL, nbkH, nbkL);              // B for cluster nf=1

        __builtin_amdgcn_s_setprio(1);
#pragma unroll
        for (int mf = 0; mf < 4; ++mf) {
            accC[mf][0] = __builtin_amdgcn_mfma_f32_16x16x32_f16(aH[mf], cbmH, accC[mf][0], 0, 0, 0);
            accC[mf][0] = __builtin_amdgcn_mfma_f32_16x16x32_f16(aH[mf], cbmL, accC[mf][0], 0, 0, 0);
            accC[mf][0] = __builtin_amdgcn_mfma_f32_16x16x32_f16(aL[mf], cbmH, accC[mf][0], 0, 0, 0);
            accP[mf][0] = __builtin_amdgcn_mfma_f32_16x16x32_f16(aH[mf], cbkH, accP[mf][0], 0, 0, 0);
            accP[mf][0] = __builtin_amdgcn_mfma_f32_16x16x32_f16(aH[mf], cbkL, accP[mf][0], 0, 0, 0);
            accP[mf][0] = __builtin_amdgcn_mfma_f32_16x16x32_f16(aL[mf], cbkH, accP[mf][0], 0, 0, 0);
        }
        __builtin_amdgcn_s_setprio(0);

        if (ks < 7) {                                      // stage next A (vmcnt covered by cluster 0)
            *(f16x8*)&sA[b ^ 1][sub8 * 512 + sl * 8] = raH;
            *(f16x8*)&sA[b ^ 1][4096 + sub8 * 512 + sl * 8] = raL;
            loadB(ks + 1, 0, cbmH, cbmL, cbkH, cbkL);      // B for next ks cluster nf=0
        }

        __builtin_amdgcn_s_setprio(1);
#pragma unroll
        for (int mf = 0; mf < 4; ++mf) {
            accC[mf][1] = __builtin_amdgcn_mfma_f32_16x16x32_f16(aH[mf], nbmH, accC[mf][1], 0, 0, 0);
            accC[mf][1] = __builtin_amdgcn_mfma_f32_16x16x32_f16(aH[mf], nbmL, accC[mf][1], 0, 0, 0);
            accC[mf][1] = __builtin_amdgcn_mfma_f32_16x16x32_f16(aL[mf], nbmH, accC[mf][1], 0, 0, 0);
            accP[mf][1] = __builtin_amdgcn_mfma_f32_16x16x32_f16(aH[mf], nbkH, accP[mf][1], 0, 0, 0);
            accP[mf][1] = __builtin_amdgcn_mfma_f32_16x16x32_f16(aH[mf], nbkL, accP[mf][1], 0, 0, 0);
            accP[mf][1] = __builtin_amdgcn_mfma_f32_16x16x32_f16(aL[mf], nbkH, accP[mf][1], 0, 0, 0);
        }
        __builtin_amdgcn_s_setprio(0);
        __syncthreads();
    }

    // epilogue: w = __expf(-dsq*inv2s2); cos via revolutions + fract + deg-8 poly
    float rs[16];
#pragma unroll
    for (int i = 0; i < 16; ++i) rs[i] = 0.f;

#pragma unroll
    for (int mf = 0; mf < 4; ++mf) {
#pragma unroll
        for (int nf = 0; nf < 2; ++nf) {
            const int cloc = wc * 32 + nf * 16 + lr;
            const float msq = sMusq[cloc], il2 = sInv[cloc], prv = sPrv[cloc];
            f32x4 c = accC[mf][nf], p = accP[mf][nf];
#pragma unroll
            for (int rg = 0; rg < 4; ++rg) {
                const int rowl = wr * 64 + mf * 16 + lg * 4 + rg;
                float dsq = fmaxf(sZsq[rowl] + msq - 2.0f * c[rg], 0.f);
                float w = __expf(-dsq * il2);
                float ph = __builtin_fmaf(p[rg], INV2PI, prv);
                float r = ph - floorf(ph);
                float uu = r - 0.5f;
                float s = uu * uu;
                float cs = 0.28203f;
                cs = __builtin_fmaf(cs, s, -1.71437f);
                cs = __builtin_fmaf(cs, s, 7.90348f);
                cs = __builtin_fmaf(cs, s, -26.42626f);
                cs = __builtin_fmaf(cs, s, 60.24464f);
                cs = __builtin_fmaf(cs, s, -85.45681720669371f);
                cs = __builtin_fmaf(cs, s, 64.93939402266829f);
                cs = __builtin_fmaf(cs, s, -19.739208802178716f);
                cs = __builtin_fmaf(cs, s, 1.0f);
                out[(size_t)(rbase + rowl) * R_DIM + cbase + cloc] = -(w * cs);
                rs[mf * 4 + rg] += w;
            }
        }
    }
#pragma unroll
    for (int i = 0; i < 16; ++i) {
#pragma unroll
        for (int sh = 1; sh < 16; sh <<= 1) rs[i] += __shfl_xor(rs[i], sh, 64);
    }
    if (lr == 0) {
#pragma unroll
        for (int mf = 0; mf < 4; ++mf)
#pragma unroll
            for (int rg = 0; rg < 4; ++rg)
                sRow[wc][wr * 64 + mf * 16 + lg * 4 + rg] = rs[mf * 4 + rg];
    }
    __syncthreads();
    if (tid < 128)
        atomicAdd(&panelSum[(size_t)mb * 128 + tid],
                  sRow[0][tid] + sRow[1][tid] + sRow[2][tid] + sRow[3][tid]);

    // publish: all out stores + sum adds visible, then bump the panel counter
    __threadfence();
    __syncthreads();
    if (tid == 0) {
        int old = __hip_atomic_fetch_add(&panelCnt[mb], 1, __ATOMIC_ACQ_REL,
                                         __HIP_MEMORY_SCOPE_AGENT);
        sLast = (old == 7);
    }
    __syncthreads();
    if (!sLast) return;

    // last block of the panel: normalize the whole 128x1024 slice (L2-hot)
    (void)__hip_atomic_load(&panelCnt[mb], __ATOMIC_ACQUIRE, __HIP_MEMORY_SCOPE_AGENT);
    if (tid < 128) {
        float s = __hip_atomic_load(&panelSum[(size_t)mb * 128 + tid], __ATOMIC_ACQUIRE,
                                    __HIP_MEMORY_SCOPE_AGENT);
        sInvN[tid] = 1.0f / fmaxf(s, 1e-6f);
    }
    __syncthreads();
    float4* obase = (float4*)(out + (size_t)rbase * R_DIM);
#pragma unroll 4
    for (int i = 0; i < 64; ++i) {
        const int j = i * 512 + tid;     // 0..32767
        const int row = j >> 8, c4 = j & 255;
        const float inv = sInvN[row];
        float4 v = obase[row * 256 + c4];
        v.x *= inv; v.y *= inv; v.z *= inv; v.w *= inv;
        obase[row * 256 + c4] = v;
    }
}

extern "C" void kernel_launch(void* const* d_in, const int* in_sizes, int n_in,
                              void* d_out, int out_size, void* d_ws, size_t ws_size,
                              hipStream_t stream) {
    const float* z    = (const float*)d_in[0];
    const float* mu   = (const float*)d_in[1];
    const float* Kmat = (const float*)d_in[2];
    const float* ls   = (const float*)d_in[3];
    const float* phi  = (const float*)d_in[4];
    float* out = (float*)d_out;
    float* ws = (float*)d_ws;
    float* zsq      = ws;                        // 16384
    float* musq     = ws + 16384;                // 1024
    float* i2s      = ws + 17408;                // 1024
    float* phirev   = ws + 18432;                // 1024
    float* panelSum = ws + 19456;                // 128*128 floats
    int*   panelCnt = (int*)(ws + 35840);        // 128 ints
    _Float16* zf  = (_Float16*)(ws + 150528);    // 16384*512 halves (fragment order)
    _Float16* muf = zf + 8388608;                // 1024*512
    _Float16* kf  = muf + 524288;                // 1024*512
    const bool pre = ws_size >= 19476480ull;

    // zero panelSum + panelCnt (harness poisons ws; must be zero every call)
    hipMemsetAsync(panelSum, 0, (16384 + 128) * sizeof(float), stream);
    hipLaunchKernelGGL(gabor_prep, dim3(4096 + 256), dim3(256), 0, stream,
                       z, mu, ls, phi, zsq, musq, i2s, phirev);
    if (pre) {
        hipLaunchKernelGGL(gabor_split, dim3(2304), dim3(256), 0, stream,
                           z, mu, Kmat, zf, muf, kf);
        hipLaunchKernelGGL(gabor_main<true>, dim3(1024), dim3(512), 0, stream,
                           z, mu, Kmat, zf, muf, kf, zsq, musq, i2s, phirev, out,
                           panelSum, panelCnt);
    } else {
        hipLaunchKernelGGL(gabor_main<false>, dim3(1024), dim3(512), 0, stream,
                           z, mu, Kmat, zf, muf, kf, zsq, musq, i2s, phirev, out,
                           panelSum, panelCnt);
    }
}

// Round 7
// 90.258 us; speedup vs baseline: 3.8869x; 3.8869x over previous
//
#include <hip/hip_runtime.h>

// GaborBasis: out[b,t,r] = window_norm * cos(z·K[r] + phi[r]),
//   window = exp(-max(|z|^2+|mu_r|^2-2 z·mu_r,0)/(2 sigma_r^2)), normalized over r.
// fp16 hi/lo 3-term split MFMA (16x16x32); fast-math epilogue.
// Round 7: block = 32 rows x ALL 1024 cols -> row-sum + normalization are
// block-LOCAL (round 6's cross-block fences/atomics cost 275us). A panel
// (32x256 hi/lo = 32KB) staged in LDS ONCE -> the whole GEMM loop is
// barrier-free; B (mu/K) fragments stream from L2 with rolling reg prefetch.
// Tail: block rescales its own 128KB output (overlaps other blocks' compute).

typedef _Float16 f16x8 __attribute__((ext_vector_type(8)));
typedef float f32x4 __attribute__((ext_vector_type(4)));

#define M_DIM 16384
#define R_DIM 1024
#define INV2PI 0.15915494309189535f

// ---------------- prep: z_sq[16384], mu_sq[1024], inv2s2[1024], phirev[1024] ----------------
__global__ void gabor_prep(const float* __restrict__ z, const float* __restrict__ mu,
                           const float* __restrict__ ls, const float* __restrict__ phi,
                           float* __restrict__ zsq, float* __restrict__ musq,
                           float* __restrict__ inv2s2, float* __restrict__ phirev) {
    const int lane = threadIdx.x & 63;
    const int wv = threadIdx.x >> 6;
    const int bid = blockIdx.x;
    if (bid < 4096) {
        const int row = bid * 4 + wv;
        float4 v = *(const float4*)(z + (size_t)row * 256 + lane * 4);
        float s = v.x * v.x + v.y * v.y + v.z * v.z + v.w * v.w;
#pragma unroll
        for (int sh = 1; sh < 64; sh <<= 1) s += __shfl_xor(s, sh, 64);
        if (lane == 0) zsq[row] = s;
    } else {
        const int row = (bid - 4096) * 4 + wv;
        float4 v = *(const float4*)(mu + (size_t)row * 256 + lane * 4);
        float s = v.x * v.x + v.y * v.y + v.z * v.z + v.w * v.w;
#pragma unroll
        for (int sh = 1; sh < 64; sh <<= 1) s += __shfl_xor(s, sh, 64);
        if (lane == 0) {
            musq[row] = s;
            float e = expf(ls[row]);
            inv2s2[row] = 1.0f / (2.0f * (e * e + 1e-8f));
            phirev[row] = phi[row] * INV2PI;
        }
    }
}

// ---------------- split: fp32 -> fp16 hi/lo in MFMA-fragment order ----------------
// Layout per matrix: [sub = row/16][ks = k/32][1024 halves]: hi at lane*8, lo at 512+lane*8,
// lane = (row&15) | ((k>>3 & 3)<<4). One thread = one (sub,ks,lane) = 8 fp32.
__global__ void gabor_split(const float* __restrict__ z, const float* __restrict__ mu,
                            const float* __restrict__ Kmat,
                            _Float16* __restrict__ zf, _Float16* __restrict__ muf,
                            _Float16* __restrict__ kf) {
    const int t = blockIdx.x * 256 + threadIdx.x;   // 0..589823
    const float* src; _Float16* dst; int item;
    if (t < 524288)      { item = t;          src = z;    dst = zf; }
    else if (t < 557056) { item = t - 524288; src = mu;   dst = muf; }
    else                 { item = t - 557056; src = Kmat; dst = kf; }
    const int sub = item >> 9, rem = item & 511;
    const int ks = rem >> 6, l = rem & 63;
    const int row = sub * 16 + (l & 15);
    const int k0 = ks * 32 + (l >> 4) * 8;
    const float* sp = src + (size_t)row * 256 + k0;
    float v[8];
    *(float4*)&v[0] = *(const float4*)(sp);
    *(float4*)&v[4] = *(const float4*)(sp + 4);
    f16x8 hi, lo;
#pragma unroll
    for (int j = 0; j < 8; ++j) {
        _Float16 h = (_Float16)v[j];
        hi[j] = h;
        lo[j] = (_Float16)(v[j] - (float)h);
    }
    _Float16* d = dst + (size_t)(sub * 8 + ks) * 1024;
    *(f16x8*)(d + l * 8) = hi;
    *(f16x8*)(d + 512 + l * 8) = lo;
}

// ---------------- main: 512 blocks x 256 thr (4 waves). Block = 32 rows x 1024 cols. ----------------
// Wave = 32 rows x 32 cols per chunk; 8 chunks of 128 cols. Barrier-free K loop.
template <bool PRE>
__global__ __launch_bounds__(256, 3) void gabor_main(
    const float* __restrict__ z, const float* __restrict__ mu, const float* __restrict__ Kmat,
    const _Float16* __restrict__ zf, const _Float16* __restrict__ muf, const _Float16* __restrict__ kf,
    const float* __restrict__ zsq, const float* __restrict__ musq,
    const float* __restrict__ inv2s2, const float* __restrict__ phirev,
    float* __restrict__ out) {
    __shared__ _Float16 sA[16384];      // [sub 0..1][ks 0..7][1024]: hi lane*8, lo 512+lane*8
    __shared__ float sZsq[32];
    __shared__ float sRow[4][32];
    __shared__ float sInvN[32];

    const int tid = threadIdx.x;
    const int bid = blockIdx.x;
    const int rbase = bid * 32;

    // ---- stage A panel (32 rows x 256 k, hi/lo) ONCE ----
    if constexpr (PRE) {
        const _Float16* zsrc = zf + (size_t)(bid * 2 * 8) * 1024;   // sub = rbase/16
#pragma unroll
        for (int j = 0; j < 8; ++j) {
            const int o = (j * 256 + tid) * 8;                      // 16B units, coalesced
            *(f16x8*)&sA[o] = *(const f16x8*)(zsrc + o);
        }
    } else {
#pragma unroll
        for (int j = 0; j < 4; ++j) {
            const int it = tid + j * 256;                            // 0..1023
            const int sub = it >> 9, rem = it & 511;
            const int ks = rem >> 6, l = rem & 63;
            const int row = rbase + sub * 16 + (l & 15);
            const float* sp = z + (size_t)row * 256 + ks * 32 + (l >> 4) * 8;
            float v[8];
            *(float4*)&v[0] = *(const float4*)(sp);
            *(float4*)&v[4] = *(const float4*)(sp + 4);
            f16x8 hi, lo;
#pragma unroll
            for (int q = 0; q < 8; ++q) {
                _Float16 h = (_Float16)v[q];
                hi[q] = h; lo[q] = (_Float16)(v[q] - (float)h);
            }
            const int o = (sub * 8 + ks) * 1024 + l * 8;
            *(f16x8*)&sA[o] = hi;
            *(f16x8*)&sA[o + 512] = lo;
        }
    }
    if (tid < 32) sZsq[tid] = zsq[rbase + tid];
    __syncthreads();                       // the ONLY barrier before the tail

    const int lane = tid & 63;
    const int wv = tid >> 6;               // 0..3 (column slot within a chunk)
    const int lr = lane & 15, lg = lane >> 4;

    float rs[8];
#pragma unroll
    for (int i = 0; i < 8; ++i) rs[i] = 0.f;

    // B register sets: [mu0H, mu0L, mu1H, mu1L, k0H, k0L, k1H, k1L]
    f16x8 Bc[8], Bn[8];
    auto loadB = [&](f16x8* d, int c, int ks) {
        if constexpr (PRE) {
            const size_t sb = (size_t)((c * 8 + wv * 2) * 8 + ks) * 1024 + lane * 8;
            const _Float16* mp = muf + sb;
            d[0] = *(const f16x8*)(mp);
            d[1] = *(const f16x8*)(mp + 512);
            d[2] = *(const f16x8*)(mp + 8192);
            d[3] = *(const f16x8*)(mp + 8192 + 512);
            const _Float16* kp = kf + sb;
            d[4] = *(const f16x8*)(kp);
            d[5] = *(const f16x8*)(kp + 512);
            d[6] = *(const f16x8*)(kp + 8192);
            d[7] = *(const f16x8*)(kp + 8192 + 512);
        } else {
#pragma unroll
            for (int n = 0; n < 2; ++n) {
                const int col = c * 128 + wv * 32 + n * 16 + lr;
                const int k0 = ks * 32 + lg * 8;
                float v[8];
                const float* sp = mu + (size_t)col * 256 + k0;
                *(float4*)&v[0] = *(const float4*)(sp);
                *(float4*)&v[4] = *(const float4*)(sp + 4);
#pragma unroll
                for (int q = 0; q < 8; ++q) {
                    _Float16 h = (_Float16)v[q];
                    d[n * 2][q] = h; d[n * 2 + 1][q] = (_Float16)(v[q] - (float)h);
                }
                const float* sp2 = Kmat + (size_t)col * 256 + k0;
                *(float4*)&v[0] = *(const float4*)(sp2);
                *(float4*)&v[4] = *(const float4*)(sp2 + 4);
#pragma unroll
                for (int q = 0; q < 8; ++q) {
                    _Float16 h = (_Float16)v[q];
                    d[4 + n * 2][q] = h; d[4 + n * 2 + 1][q] = (_Float16)(v[q] - (float)h);
                }
            }
        }
    };

    loadB(Bc, 0, 0);

#pragma unroll 1
    for (int c = 0; c < 8; ++c) {
        f32x4 accC[2][2], accP[2][2];
#pragma unroll
        for (int m = 0; m < 2; ++m)
#pragma unroll
            for (int n = 0; n < 2; ++n) {
                accC[m][n] = (f32x4){0.f, 0.f, 0.f, 0.f};
                accP[m][n] = (f32x4){0.f, 0.f, 0.f, 0.f};
            }

#pragma unroll
        for (int ks = 0; ks < 8; ++ks) {
            // A fragments from LDS (lane-linear, conflict-free)
            f16x8 aH[2], aL[2];
#pragma unroll
            for (int m = 0; m < 2; ++m) {
                const int o = (m * 8 + ks) * 1024 + lane * 8;
                aH[m] = *(const f16x8*)&sA[o];
                aL[m] = *(const f16x8*)&sA[o + 512];
            }
            // rolling B prefetch (next ks, or next chunk's ks=0)
            const bool last = (c == 7) && (ks == 7);
            if (!last) loadB(Bn, ks < 7 ? c : c + 1, (ks + 1) & 7);

            __builtin_amdgcn_s_setprio(1);
#pragma unroll
            for (int m = 0; m < 2; ++m)
#pragma unroll
                for (int n = 0; n < 2; ++n) {
                    accC[m][n] = __builtin_amdgcn_mfma_f32_16x16x32_f16(aH[m], Bc[n * 2],     accC[m][n], 0, 0, 0);
                    accC[m][n] = __builtin_amdgcn_mfma_f32_16x16x32_f16(aH[m], Bc[n * 2 + 1], accC[m][n], 0, 0, 0);
                    accC[m][n] = __builtin_amdgcn_mfma_f32_16x16x32_f16(aL[m], Bc[n * 2],     accC[m][n], 0, 0, 0);
                    accP[m][n] = __builtin_amdgcn_mfma_f32_16x16x32_f16(aH[m], Bc[4 + n * 2],     accP[m][n], 0, 0, 0);
                    accP[m][n] = __builtin_amdgcn_mfma_f32_16x16x32_f16(aH[m], Bc[4 + n * 2 + 1], accP[m][n], 0, 0, 0);
                    accP[m][n] = __builtin_amdgcn_mfma_f32_16x16x32_f16(aL[m], Bc[4 + n * 2],     accP[m][n], 0, 0, 0);
                }
            __builtin_amdgcn_s_setprio(0);
#pragma unroll
            for (int i = 0; i < 8; ++i) Bc[i] = Bn[i];
        }

        // ---- per-chunk epilogue: w, cos, unnormalized write, row-sum accumulate ----
#pragma unroll
        for (int m = 0; m < 2; ++m)
#pragma unroll
            for (int n = 0; n < 2; ++n) {
                const int col = c * 128 + wv * 32 + n * 16 + lr;
                const float msq = musq[col], il2 = inv2s2[col], prv = phirev[col];
                f32x4 cc = accC[m][n], pp = accP[m][n];
#pragma unroll
                for (int rg = 0; rg < 4; ++rg) {
                    const int rowl = m * 16 + lg * 4 + rg;
                    float dsq = fmaxf(sZsq[rowl] + msq - 2.0f * cc[rg], 0.f);
                    float w = __expf(-dsq * il2);
                    float ph = __builtin_fmaf(pp[rg], INV2PI, prv);
                    float r = ph - floorf(ph);
                    float uu = r - 0.5f;
                    float s = uu * uu;
                    float cs = 0.28203f;
                    cs = __builtin_fmaf(cs, s, -1.71437f);
                    cs = __builtin_fmaf(cs, s, 7.90348f);
                    cs = __builtin_fmaf(cs, s, -26.42626f);
                    cs = __builtin_fmaf(cs, s, 60.24464f);
                    cs = __builtin_fmaf(cs, s, -85.45681720669371f);
                    cs = __builtin_fmaf(cs, s, 64.93939402266829f);
                    cs = __builtin_fmaf(cs, s, -19.739208802178716f);
                    cs = __builtin_fmaf(cs, s, 1.0f);
                    out[(size_t)(rbase + rowl) * R_DIM + col] = -(w * cs);
                    rs[m * 4 + rg] += w;
                }
            }
    }

    // ---- block-local row sums -> normalize own 32x1024 tile ----
#pragma unroll
    for (int i = 0; i < 8; ++i) {
#pragma unroll
        for (int sh = 1; sh < 16; sh <<= 1) rs[i] += __shfl_xor(rs[i], sh, 64);
    }
    if (lr == 0) {
#pragma unroll
        for (int m = 0; m < 2; ++m)
#pragma unroll
            for (int rg = 0; rg < 4; ++rg)
                sRow[wv][m * 16 + lg * 4 + rg] = rs[m * 4 + rg];
    }
    __syncthreads();
    if (tid < 32)
        sInvN[tid] = 1.0f / fmaxf(sRow[0][tid] + sRow[1][tid] + sRow[2][tid] + sRow[3][tid], 1e-6f);
    __threadfence_block();
    __syncthreads();

    float4* obase = (float4*)(out + (size_t)rbase * R_DIM);
#pragma unroll 4
    for (int j = 0; j < 32; ++j) {
        const int idx = j * 256 + tid;        // 0..8191 float4s
        const int row = idx >> 8, c4 = idx & 255;
        const float inv = sInvN[row];
        float4 v = obase[row * 256 + c4];
        v.x *= inv; v.y *= inv; v.z *= inv; v.w *= inv;
        obase[row * 256 + c4] = v;
    }
}

extern "C" void kernel_launch(void* const* d_in, const int* in_sizes, int n_in,
                              void* d_out, int out_size, void* d_ws, size_t ws_size,
                              hipStream_t stream) {
    const float* z    = (const float*)d_in[0];
    const float* mu   = (const float*)d_in[1];
    const float* Kmat = (const float*)d_in[2];
    const float* ls   = (const float*)d_in[3];
    const float* phi  = (const float*)d_in[4];
    float* out = (float*)d_out;
    float* ws = (float*)d_ws;
    float* zsq      = ws;                        // 16384
    float* musq     = ws + 16384;                // 1024
    float* i2s      = ws + 17408;                // 1024
    float* phirev   = ws + 18432;                // 1024
    _Float16* zf  = (_Float16*)(ws + 150528);    // 16384*512 halves (fragment order)
    _Float16* muf = zf + 8388608;                // 1024*512
    _Float16* kf  = muf + 524288;                // 1024*512
    const bool pre = ws_size >= 19476480ull;

    hipLaunchKernelGGL(gabor_prep, dim3(4096 + 256), dim3(256), 0, stream,
                       z, mu, ls, phi, zsq, musq, i2s, phirev);
    if (pre) {
        hipLaunchKernelGGL(gabor_split, dim3(2304), dim3(256), 0, stream,
                           z, mu, Kmat, zf, muf, kf);
        hipLaunchKernelGGL(gabor_main<true>, dim3(M_DIM / 32), dim3(256), 0, stream,
                           z, mu, Kmat, zf, muf, kf, zsq, musq, i2s, phirev, out);
    } else {
        hipLaunchKernelGGL(gabor_main<false>, dim3(M_DIM / 32), dim3(256), 0, stream,
                           z, mu, Kmat, zf, muf, kf, zsq, musq, i2s, phirev, out);
    }
}